// Round 4
// baseline (192.585 us; speedup 1.0000x reference)
//
#include <hip/hip_runtime.h>
#include <hip/hip_bf16.h>

// BatchedNLM: per-neuron 2-layer GLU MLP.
//   state_trace (128,2048,32) f32, fc1_w (2048,32,256), fc1_b (2048,256),
//   fc2_w (2048,128,2), fc2_b (2048,2), T (1)  ->  out (128,2048) f32
//
// One block per neuron. 256 threads = 4 waves; wave w owns batches [32w,32w+32).
// GEMM1 via mfma_f32_16x16x32_bf16 (K=32 in a single MFMA, acc from 0).
// GLU1 pairs (h, h+128) = tiles (p, p+8): same lane, same acc reg -> register-only.
// fc2 (K=128, N=2) folded into the tile loop as per-lane partials + shfl_xor tree.
//
// R2: coalesced 512B row into out_t (2048,128) in d_ws + transpose kernel.
// R3: __launch_bounds__(256,4) — (256,8) forced VGPR 64->32 + 500 MB spills.
// R4: p-loop had 32 per-thread GLOBAL scalar loads (b1/w2) that the compiler
//     did not hoist (VGPR=64) -> per-iteration vmcnt stalls = the 24% VALUBusy /
//     2.1 TB/s latency-bound profile. Now staged as a float4 LDS table; loop is
//     pure LDS+MFMA+VALU. Packed v_cvt_pk_bf16_f32 halves staging VALU. All
//     global loads issued up-front (~39 in flight).

#define NN 2048

typedef __attribute__((ext_vector_type(8))) short short8;
typedef __attribute__((ext_vector_type(4))) float floatx4;
typedef __attribute__((ext_vector_type(4))) int int4v;

static __device__ __forceinline__ unsigned int pkbf(float a, float b) {
    __hip_bfloat162 h = __float22bfloat162_rn(make_float2(a, b));  // v_cvt_pk_bf16_f32 (RNE)
    return *(unsigned int*)&h;
}

static __device__ __forceinline__ float sigmoidf(float x) {
    return 1.0f / (1.0f + __expf(-x));
}

__global__ __launch_bounds__(256, 4)
void nlm_kernel(const float* __restrict__ st,
                const float* __restrict__ w1,
                const float* __restrict__ b1,
                const float* __restrict__ w2,
                const float* __restrict__ b2,
                const float* __restrict__ Tp,
                float* __restrict__ out_t)
{
    const int n = blockIdx.x;
    const int t = threadIdx.x;

    // Fragment-major B: [tile p (16)][lane (64)][j (8)] bf16 = 16 KB.
    __shared__ short  ldsB[16 * 64 * 8];
    __shared__ float4 ldsP[128];          // {b1[h], b1[128+h], w2[2h], w2[2h+1]}
    __shared__ float  ldsO[128];

    const int lane = t & 63;
    const int wv   = t >> 6;      // wave 0..3
    const int m    = lane & 15;   // A row / C col
    const int quad = lane >> 4;   // k-quad / C row group

    // ---- Issue ALL global loads first (A-frags, params, w1), convert after ----

    // A fragments: A[m][k] = state[b][n][k], k = quad*8 + j (contiguous).
    floatx4 av[2][2];
    #pragma unroll
    for (int bt = 0; bt < 2; ++bt) {
        const int b = wv * 32 + bt * 16 + m;
        const float* sp = st + (size_t)b * (NN * 32) + (size_t)n * 32 + quad * 8;
        av[bt][0] = *(const floatx4*)sp;
        av[bt][1] = *(const floatx4*)(sp + 4);
    }

    // Param table loads (threads 0..127), all coalesced.
    const float* b1p = b1 + n * 256;
    const float* w2p = w2 + n * 256;
    float pba = 0.f, pbb = 0.f;
    float2 pw2 = make_float2(0.f, 0.f);
    if (t < 128) {
        pba = b1p[t];
        pbb = b1p[128 + t];
        pw2 = *(const float2*)(w2p + 2 * t);
    }

    // Epilogue scalars (uniform).
    const float bb0  = b2[n * 2 + 0];
    const float bb1  = b2[n * 2 + 1];
    const float invT = 1.0f / Tp[0];

    // W1[n] (32x256 f32): thread t owns column h = t; 32 strided dword loads
    // (coalesced 256B/wave-instr), batched before conversion.
    float w1t[32];
    {
        const float* wp = w1 + (size_t)n * 8192 + t;
        #pragma unroll
        for (int k = 0; k < 32; ++k)
            w1t[k] = wp[k * 256];
    }

    // ---- Convert + stage to LDS ----
    if (t < 128)
        ldsP[t] = make_float4(pba, pbb, pw2.x, pw2.y);

    {
        const int base = ((t >> 4) * 512) + ((t & 15) * 8); // shorts
        #pragma unroll
        for (int q = 0; q < 4; ++q) {
            union { int4v i; short8 s; } u;
            #pragma unroll
            for (int jj = 0; jj < 4; ++jj)
                u.i[jj] = pkbf(w1t[q * 8 + 2 * jj], w1t[q * 8 + 2 * jj + 1]);
            *(short8*)&ldsB[base + q * 128] = u.s;  // dense 1KB region: conflict-free
        }
    }

    short8 afrag[2];
    #pragma unroll
    for (int bt = 0; bt < 2; ++bt) {
        union { int4v i; short8 s; } u;
        u.i[0] = pkbf(av[bt][0][0], av[bt][0][1]);
        u.i[1] = pkbf(av[bt][0][2], av[bt][0][3]);
        u.i[2] = pkbf(av[bt][1][0], av[bt][1][1]);
        u.i[3] = pkbf(av[bt][1][2], av[bt][1][3]);
        afrag[bt] = u.s;
    }

    __syncthreads();

    // fc2 partial sums: [bt][reg(row)][o]
    float pacc[2][4][2];
    #pragma unroll
    for (int bt = 0; bt < 2; ++bt)
        #pragma unroll
        for (int r = 0; r < 4; ++r)
            pacc[bt][r][0] = pacc[bt][r][1] = 0.0f;

    #pragma unroll
    for (int p = 0; p < 8; ++p) {
        // B fragments for tile p (h = m + 16p) and p+8 (h + 128)
        short8 bfA = *(short8*)&ldsB[(p * 64 + lane) * 8];
        short8 bfB = *(short8*)&ldsB[((p + 8) * 64 + lane) * 8];

        // One ds_read_b128: {bias_a, bias_b, w2a, w2b} for h = p*16 + m.
        // 16 lanes cover 256B contiguous (banks 2-way = free); quads broadcast.
        float4 prm = ldsP[p * 16 + m];

        #pragma unroll
        for (int bt = 0; bt < 2; ++bt) {
            floatx4 z = {0.0f, 0.0f, 0.0f, 0.0f};
            floatx4 xa = __builtin_amdgcn_mfma_f32_16x16x32_bf16(afrag[bt], bfA, z, 0, 0, 0);
            floatx4 xb = __builtin_amdgcn_mfma_f32_16x16x32_bf16(afrag[bt], bfB, z, 0, 0, 0);
            #pragma unroll
            for (int r = 0; r < 4; ++r) {
                float a   = xa[r] + prm.x;
                float g   = xb[r] + prm.y;
                float glu = a * sigmoidf(g);
                pacc[bt][r][0] += glu * prm.z;
                pacc[bt][r][1] += glu * prm.w;
            }
        }
    }

    // ---- Reduce fc2 partials across the 16 lanes of each quad (over h's col idx) ----
    #pragma unroll
    for (int bt = 0; bt < 2; ++bt) {
        #pragma unroll
        for (int r = 0; r < 4; ++r) {
            float s0 = pacc[bt][r][0];
            float s1 = pacc[bt][r][1];
            s0 += __shfl_xor(s0, 1);  s1 += __shfl_xor(s1, 1);
            s0 += __shfl_xor(s0, 2);  s1 += __shfl_xor(s1, 2);
            s0 += __shfl_xor(s0, 4);  s1 += __shfl_xor(s1, 4);
            s0 += __shfl_xor(s0, 8);  s1 += __shfl_xor(s1, 8);
            if (m == 0) {
                const int b = wv * 32 + bt * 16 + quad * 4 + r;
                float x0 = s0 + bb0;
                float x1 = s1 + bb1;
                ldsO[b] = x0 * sigmoidf(x1) * invT;
            }
        }
    }

    __syncthreads();

    // One coalesced 512B row per block into out_t (2048,128).
    if (t < 128)
        out_t[(size_t)n * 128 + t] = ldsO[t];
}

// Transpose out_t (2048,128) -> out (128,2048). 32x32 tiles, 256 blocks.
__global__ __launch_bounds__(256)
void transpose_kernel(const float* __restrict__ out_t, float* __restrict__ out)
{
    __shared__ float tile[32][33];
    const int t    = threadIdx.x;
    const int bidx = blockIdx.x;           // 0..255
    const int n0   = (bidx & 63) * 32;     // 64 n-tiles
    const int b0   = (bidx >> 6) * 32;     // 4 b-tiles

    const int tx = t & 31;
    const int ty = t >> 5;                 // 0..7

    #pragma unroll
    for (int i = 0; i < 4; ++i) {
        const int nl = ty + i * 8;
        tile[nl][tx] = out_t[(size_t)(n0 + nl) * 128 + b0 + tx];
    }

    __syncthreads();

    #pragma unroll
    for (int i = 0; i < 4; ++i) {
        const int bl = ty + i * 8;
        out[(size_t)(b0 + bl) * NN + n0 + tx] = tile[tx][bl];
    }
}

extern "C" void kernel_launch(void* const* d_in, const int* in_sizes, int n_in,
                              void* d_out, int out_size, void* d_ws, size_t ws_size,
                              hipStream_t stream) {
    const float* st = (const float*)d_in[0];
    const float* w1 = (const float*)d_in[1];
    const float* b1 = (const float*)d_in[2];
    const float* w2 = (const float*)d_in[3];
    const float* b2 = (const float*)d_in[4];
    const float* T  = (const float*)d_in[5];
    float* out   = (float*)d_out;
    float* out_t = (float*)d_ws;    // 2048*128*4 = 1 MB scratch

    nlm_kernel<<<dim3(NN), dim3(256), 0, stream>>>(st, w1, b1, w2, b2, T, out_t);
    transpose_kernel<<<dim3(256), dim3(256), 0, stream>>>(out_t, out);
}

// Round 5
// 143.994 us; speedup vs baseline: 1.3374x; 1.3374x over previous
//
#include <hip/hip_runtime.h>
#include <hip/hip_bf16.h>

// BatchedNLM: per-neuron 2-layer GLU MLP.
//   state_trace (128,2048,32) f32, fc1_w (2048,32,256), fc1_b (2048,256),
//   fc2_w (2048,128,2), fc2_b (2048,2), T (1)  ->  out (128,2048) f32
//
// One block per neuron. 256 threads = 4 waves; wave w owns batches [32w,32w+32).
// GEMM1 via mfma_f32_16x16x32_bf16 (K=32 in a single MFMA, acc from 0).
// GLU1 pairs (h, h+128) = tiles (p, p+8): same lane, same acc reg -> register-only.
// fc2 (K=128, N=2) folded into the tile loop as per-lane partials + shfl_xor tree.
//
// R2: coalesced 512B row into out_t (2048,128) in d_ws + transpose kernel.
// R3: __launch_bounds__(256,4) — (256,8) forced VGPR 64->32 + 500 MB spills.
// R4 FAILED: batching 32 w1 loads in w1t[32] registers under a 64-VGPR cap made
//     the compiler spill/split them (FETCH 120->190 MB, dur unchanged). Lesson:
//     register staging cannot give deep MLP under tight VGPR budgets.
// R5: w1 staged by __builtin_amdgcn_global_load_lds width=16 — async DMA, zero
//     VGPR round-trip, whole 32 KB in flight per block from the first instr.
//     LDS f32->bf16 conversion pass (conflict-free reads) builds the same
//     fragment-major ldsB; p-loop identical to R3. launch_bounds (256,2):
//     spill-proof; occupancy is LDS-limited (~50.5 KB -> 3 blocks/CU).

#define NN 2048

typedef __attribute__((ext_vector_type(8))) short short8;
typedef __attribute__((ext_vector_type(4))) float floatx4;
typedef __attribute__((ext_vector_type(4))) int int4v;

static __device__ __forceinline__ unsigned int pkbf(float a, float b) {
    __hip_bfloat162 h = __float22bfloat162_rn(make_float2(a, b));  // v_cvt_pk_bf16_f32
    return *(unsigned int*)&h;
}

static __device__ __forceinline__ float sigmoidf(float x) {
    return 1.0f / (1.0f + __expf(-x));
}

static __device__ __forceinline__ void gload_lds16(const float* g, float* l) {
    // Per-lane gptr; LDS dest = wave-uniform base + lane*16B (m97/m104 semantics).
    __builtin_amdgcn_global_load_lds((const __attribute__((address_space(1))) void*)g,
                                     (__attribute__((address_space(3))) void*)l,
                                     16, 0, 0);
}

__global__ __launch_bounds__(256, 2)
void nlm_kernel(const float* __restrict__ st,
                const float* __restrict__ w1,
                const float* __restrict__ b1,
                const float* __restrict__ w2,
                const float* __restrict__ b2,
                const float* __restrict__ Tp,
                float* __restrict__ out_t)
{
    const int n = blockIdx.x;
    const int t = threadIdx.x;

    __shared__ __align__(16) float  ldsW[32 * 256];   // raw f32 W1[n], 32 KB
    __shared__ short  ldsB[16 * 64 * 8];              // fragment-major bf16, 16 KB
    __shared__ float4 ldsP[128];                      // {b1[h], b1[128+h], w2[2h], w2[2h+1]}
    __shared__ float  ldsO[128];

    const int lane = t & 63;
    const int wv   = t >> 6;      // wave 0..3
    const int m    = lane & 15;   // A row / C col
    const int quad = lane >> 4;   // k-quad / C row group

    // ---- 1) Async DMA: W1[n] (32 KB f32) -> ldsW. 8 instrs/wave, no VGPRs. ----
    {
        const float* gW = w1 + (size_t)n * 8192;
        #pragma unroll
        for (int i = 0; i < 8; ++i) {
            const int off = wv * 2048 + i * 256;      // floats, wave-uniform
            gload_lds16(gW + off + lane * 4, &ldsW[off]);
        }
    }

    // ---- 2) Register loads issued behind the DMA: A-frags + param table ----
    floatx4 av[2][2];
    #pragma unroll
    for (int bt = 0; bt < 2; ++bt) {
        const int b = wv * 32 + bt * 16 + m;
        const float* sp = st + (size_t)b * (NN * 32) + (size_t)n * 32 + quad * 8;
        av[bt][0] = *(const floatx4*)sp;
        av[bt][1] = *(const floatx4*)(sp + 4);
    }

    const float* b1p = b1 + n * 256;
    const float* w2p = w2 + n * 256;
    float pba = 0.f, pbb = 0.f;
    float2 pw2 = make_float2(0.f, 0.f);
    if (t < 128) {
        pba = b1p[t];
        pbb = b1p[128 + t];
        pw2 = *(const float2*)(w2p + 2 * t);
    }

    const float bb0  = b2[n * 2 + 0];
    const float bb1  = b2[n * 2 + 1];
    const float invT = 1.0f / Tp[0];

    // Convert A-frags while DMA is in flight.
    short8 afrag[2];
    #pragma unroll
    for (int bt = 0; bt < 2; ++bt) {
        union { int4v i; short8 s; } u;
        u.i[0] = pkbf(av[bt][0][0], av[bt][0][1]);
        u.i[1] = pkbf(av[bt][0][2], av[bt][0][3]);
        u.i[2] = pkbf(av[bt][1][0], av[bt][1][1]);
        u.i[3] = pkbf(av[bt][1][2], av[bt][1][3]);
        afrag[bt] = u.s;
    }
    if (t < 128)
        ldsP[t] = make_float4(pba, pbb, pw2.x, pw2.y);

    __syncthreads();   // drains DMA (vmcnt) + LDS writes

    // ---- 3) LDS conversion pass: ldsW f32 -> ldsB bf16 fragment-major ----
    // Thread t owns column h=t. Reads ldsW[k*256+t]: lanes consecutive -> 2-way
    // bank alias = free. Grouped 8 reads / 4 cvt / 1 write to bound liveness.
    {
        const int base = ((t >> 4) * 512) + ((t & 15) * 8); // shorts
        #pragma unroll
        for (int q = 0; q < 4; ++q) {
            float w[8];
            #pragma unroll
            for (int j = 0; j < 8; ++j)
                w[j] = ldsW[(q * 8 + j) * 256 + t];
            union { int4v i; short8 s; } u;
            #pragma unroll
            for (int e = 0; e < 4; ++e)
                u.i[e] = pkbf(w[2 * e], w[2 * e + 1]);
            *(short8*)&ldsB[base + q * 128] = u.s;
        }
    }

    __syncthreads();

    // ---- 4) Compute: 8 tile-pairs, fc2 folded in ----
    float pacc[2][4][2];
    #pragma unroll
    for (int bt = 0; bt < 2; ++bt)
        #pragma unroll
        for (int r = 0; r < 4; ++r)
            pacc[bt][r][0] = pacc[bt][r][1] = 0.0f;

    #pragma unroll
    for (int p = 0; p < 8; ++p) {
        short8 bfA = *(short8*)&ldsB[(p * 64 + lane) * 8];
        short8 bfB = *(short8*)&ldsB[((p + 8) * 64 + lane) * 8];
        float4 prm = ldsP[p * 16 + m];   // {bias_a, bias_b, w2a, w2b} for h=p*16+m

        #pragma unroll
        for (int bt = 0; bt < 2; ++bt) {
            floatx4 z = {0.0f, 0.0f, 0.0f, 0.0f};
            floatx4 xa = __builtin_amdgcn_mfma_f32_16x16x32_bf16(afrag[bt], bfA, z, 0, 0, 0);
            floatx4 xb = __builtin_amdgcn_mfma_f32_16x16x32_bf16(afrag[bt], bfB, z, 0, 0, 0);
            #pragma unroll
            for (int r = 0; r < 4; ++r) {
                float a   = xa[r] + prm.x;
                float g   = xb[r] + prm.y;
                float glu = a * sigmoidf(g);
                pacc[bt][r][0] += glu * prm.z;
                pacc[bt][r][1] += glu * prm.w;
            }
        }
    }

    // ---- 5) Reduce fc2 partials across the 16 lanes of each quad ----
    #pragma unroll
    for (int bt = 0; bt < 2; ++bt) {
        #pragma unroll
        for (int r = 0; r < 4; ++r) {
            float s0 = pacc[bt][r][0];
            float s1 = pacc[bt][r][1];
            s0 += __shfl_xor(s0, 1);  s1 += __shfl_xor(s1, 1);
            s0 += __shfl_xor(s0, 2);  s1 += __shfl_xor(s1, 2);
            s0 += __shfl_xor(s0, 4);  s1 += __shfl_xor(s1, 4);
            s0 += __shfl_xor(s0, 8);  s1 += __shfl_xor(s1, 8);
            if (m == 0) {
                const int b = wv * 32 + bt * 16 + quad * 4 + r;
                float x0 = s0 + bb0;
                float x1 = s1 + bb1;
                ldsO[b] = x0 * sigmoidf(x1) * invT;
            }
        }
    }

    __syncthreads();

    // One coalesced 512B row per block into out_t (2048,128).
    if (t < 128)
        out_t[(size_t)n * 128 + t] = ldsO[t];
}

// Transpose out_t (2048,128) -> out (128,2048). 32x32 tiles, 256 blocks.
__global__ __launch_bounds__(256)
void transpose_kernel(const float* __restrict__ out_t, float* __restrict__ out)
{
    __shared__ float tile[32][33];
    const int t    = threadIdx.x;
    const int bidx = blockIdx.x;           // 0..255
    const int n0   = (bidx & 63) * 32;     // 64 n-tiles
    const int b0   = (bidx >> 6) * 32;     // 4 b-tiles

    const int tx = t & 31;
    const int ty = t >> 5;                 // 0..7

    #pragma unroll
    for (int i = 0; i < 4; ++i) {
        const int nl = ty + i * 8;
        tile[nl][tx] = out_t[(size_t)(n0 + nl) * 128 + b0 + tx];
    }

    __syncthreads();

    #pragma unroll
    for (int i = 0; i < 4; ++i) {
        const int bl = ty + i * 8;
        out[(size_t)(b0 + bl) * NN + n0 + tx] = tile[tx][bl];
    }
}

extern "C" void kernel_launch(void* const* d_in, const int* in_sizes, int n_in,
                              void* d_out, int out_size, void* d_ws, size_t ws_size,
                              hipStream_t stream) {
    const float* st = (const float*)d_in[0];
    const float* w1 = (const float*)d_in[1];
    const float* b1 = (const float*)d_in[2];
    const float* w2 = (const float*)d_in[3];
    const float* b2 = (const float*)d_in[4];
    const float* T  = (const float*)d_in[5];
    float* out   = (float*)d_out;
    float* out_t = (float*)d_ws;    // 2048*128*4 = 1 MB scratch

    nlm_kernel<<<dim3(NN), dim3(256), 0, stream>>>(st, w1, b1, w2, b2, T, out_t);
    transpose_kernel<<<dim3(256), dim3(256), 0, stream>>>(out_t, out);
}

// Round 6
// 132.982 us; speedup vs baseline: 1.4482x; 1.0828x over previous
//
#include <hip/hip_runtime.h>
#include <hip/hip_bf16.h>

// BatchedNLM: per-neuron 2-layer GLU MLP.
//   state_trace (128,2048,32) f32, fc1_w (2048,32,256), fc1_b (2048,256),
//   fc2_w (2048,128,2), fc2_b (2048,2), T (1)  ->  out (128,2048) f32
//
// One block per neuron. 256 threads = 4 waves; wave w owns batches [32w,32w+32).
// GEMM1 via mfma_f32_16x16x32_bf16 (K=32 in a single MFMA, acc from 0).
// GLU1 pairs (h, h+128) = tiles (p, p+8): same lane, same acc reg -> register-only.
// fc2 (K=128, N=2) folded into the tile loop as per-lane partials + shfl_xor tree.
//
// R2: coalesced 512B row into out_t (2048,128) in d_ws + transpose kernel.
// R3: __launch_bounds__(256,4) — (256,8) forced VGPR 64->32 + 500 MB spills.
// R4 FAILED: register-batching w1 loads under 64-VGPR cap -> spills.
// R5 WIN (94->46 us): w1 via global_load_lds width=16 (async DMA, no VGPRs).
//     Counters: HBM 1.1 TB/s, FETCH 51 MB (L3-warm), VALUBusy 45%, Occ 18%
//     -> VALU/latency-bound now.
// R6: (a) sigmoid = rcp(1+exp) via __builtin_amdgcn_rcpf — the 1/x was
//     compiling to the ~9-op IEEE div sequence x65 GLU evals/thread.
//     (b) ldsB aliased onto ldsW (conversion goes through registers across a
//     barrier): LDS 51.7 -> 35.3 KB -> 4 blocks/CU instead of 3.

#define NN 2048

typedef __attribute__((ext_vector_type(8))) short short8;
typedef __attribute__((ext_vector_type(4))) float floatx4;
typedef __attribute__((ext_vector_type(4))) int int4v;

static __device__ __forceinline__ unsigned int pkbf(float a, float b) {
    __hip_bfloat162 h = __float22bfloat162_rn(make_float2(a, b));  // v_cvt_pk_bf16_f32
    return *(unsigned int*)&h;
}

static __device__ __forceinline__ float sigmoidf(float x) {
    // v_mul + v_exp + v_add + v_rcp (NOT the IEEE div sequence)
    return __builtin_amdgcn_rcpf(1.0f + __expf(-x));
}

static __device__ __forceinline__ void gload_lds16(const float* g, float* l) {
    // Per-lane gptr; LDS dest = wave-uniform base + lane*16B (m97/m104 semantics).
    __builtin_amdgcn_global_load_lds((const __attribute__((address_space(1))) void*)g,
                                     (__attribute__((address_space(3))) void*)l,
                                     16, 0, 0);
}

__global__ __launch_bounds__(256, 2)
void nlm_kernel(const float* __restrict__ st,
                const float* __restrict__ w1,
                const float* __restrict__ b1,
                const float* __restrict__ w2,
                const float* __restrict__ b2,
                const float* __restrict__ Tp,
                float* __restrict__ out_t)
{
    const int n = blockIdx.x;
    const int t = threadIdx.x;

    // ldsW: raw f32 W1[n] (32 KB). After the register-held conversion pass its
    // first 16 KB is REUSED as the fragment-major bf16 buffer (ldsB).
    __shared__ __align__(16) float  ldsW[32 * 256];
    __shared__ float4 ldsP[128];          // {b1[h], b1[128+h], w2[2h], w2[2h+1]}
    __shared__ float  ldsO[128];
    short* ldsB = (short*)ldsW;

    const int lane = t & 63;
    const int wv   = t >> 6;      // wave 0..3
    const int m    = lane & 15;   // A row / C col
    const int quad = lane >> 4;   // k-quad / C row group

    // ---- 1) Async DMA: W1[n] (32 KB f32) -> ldsW. 8 instrs/wave, no VGPRs. ----
    {
        const float* gW = w1 + (size_t)n * 8192;
        #pragma unroll
        for (int i = 0; i < 8; ++i) {
            const int off = wv * 2048 + i * 256;      // floats, wave-uniform
            gload_lds16(gW + off + lane * 4, &ldsW[off]);
        }
    }

    // ---- 2) Register loads issued behind the DMA: A-frags + param table ----
    floatx4 av[2][2];
    #pragma unroll
    for (int bt = 0; bt < 2; ++bt) {
        const int b = wv * 32 + bt * 16 + m;
        const float* sp = st + (size_t)b * (NN * 32) + (size_t)n * 32 + quad * 8;
        av[bt][0] = *(const floatx4*)sp;
        av[bt][1] = *(const floatx4*)(sp + 4);
    }

    const float* b1p = b1 + n * 256;
    const float* w2p = w2 + n * 256;
    float pba = 0.f, pbb = 0.f;
    float2 pw2 = make_float2(0.f, 0.f);
    if (t < 128) {
        pba = b1p[t];
        pbb = b1p[128 + t];
        pw2 = *(const float2*)(w2p + 2 * t);
    }

    const float bb0  = b2[n * 2 + 0];
    const float bb1  = b2[n * 2 + 1];
    const float invT = 1.0f / Tp[0];

    // Convert A-frags while DMA is in flight.
    short8 afrag[2];
    #pragma unroll
    for (int bt = 0; bt < 2; ++bt) {
        union { int4v i; short8 s; } u;
        u.i[0] = pkbf(av[bt][0][0], av[bt][0][1]);
        u.i[1] = pkbf(av[bt][0][2], av[bt][0][3]);
        u.i[2] = pkbf(av[bt][1][0], av[bt][1][1]);
        u.i[3] = pkbf(av[bt][1][2], av[bt][1][3]);
        afrag[bt] = u.s;
    }
    if (t < 128)
        ldsP[t] = make_float4(pba, pbb, pw2.x, pw2.y);

    __syncthreads();   // drains DMA (vmcnt) + LDS writes

    // ---- 3) In-place conversion: ldsW f32 -> registers -> ldsB bf16 ----
    // Thread t owns column h=t. Reads ldsW[k*256+t]: lanes consecutive -> 2-way
    // bank alias = free. All reads complete (barrier) before bf16 overwrite.
    float w[32];
    #pragma unroll
    for (int k = 0; k < 32; ++k)
        w[k] = ldsW[k * 256 + t];

    __syncthreads();   // everyone done reading f32 before bf16 overwrite

    {
        const int base = ((t >> 4) * 512) + ((t & 15) * 8); // shorts
        #pragma unroll
        for (int q = 0; q < 4; ++q) {
            union { int4v i; short8 s; } u;
            #pragma unroll
            for (int e = 0; e < 4; ++e)
                u.i[e] = pkbf(w[q * 8 + 2 * e], w[q * 8 + 2 * e + 1]);
            *(short8*)&ldsB[base + q * 128] = u.s;
        }
    }

    __syncthreads();

    // ---- 4) Compute: 8 tile-pairs, fc2 folded in ----
    float pacc[2][4][2];
    #pragma unroll
    for (int bt = 0; bt < 2; ++bt)
        #pragma unroll
        for (int r = 0; r < 4; ++r)
            pacc[bt][r][0] = pacc[bt][r][1] = 0.0f;

    #pragma unroll
    for (int p = 0; p < 8; ++p) {
        short8 bfA = *(short8*)&ldsB[(p * 64 + lane) * 8];
        short8 bfB = *(short8*)&ldsB[((p + 8) * 64 + lane) * 8];
        float4 prm = ldsP[p * 16 + m];   // {bias_a, bias_b, w2a, w2b} for h=p*16+m

        #pragma unroll
        for (int bt = 0; bt < 2; ++bt) {
            floatx4 z = {0.0f, 0.0f, 0.0f, 0.0f};
            floatx4 xa = __builtin_amdgcn_mfma_f32_16x16x32_bf16(afrag[bt], bfA, z, 0, 0, 0);
            floatx4 xb = __builtin_amdgcn_mfma_f32_16x16x32_bf16(afrag[bt], bfB, z, 0, 0, 0);
            #pragma unroll
            for (int r = 0; r < 4; ++r) {
                float a   = xa[r] + prm.x;
                float g   = xb[r] + prm.y;
                float glu = a * sigmoidf(g);
                pacc[bt][r][0] += glu * prm.z;
                pacc[bt][r][1] += glu * prm.w;
            }
        }
    }

    // ---- 5) Reduce fc2 partials across the 16 lanes of each quad ----
    #pragma unroll
    for (int bt = 0; bt < 2; ++bt) {
        #pragma unroll
        for (int r = 0; r < 4; ++r) {
            float s0 = pacc[bt][r][0];
            float s1 = pacc[bt][r][1];
            s0 += __shfl_xor(s0, 1);  s1 += __shfl_xor(s1, 1);
            s0 += __shfl_xor(s0, 2);  s1 += __shfl_xor(s1, 2);
            s0 += __shfl_xor(s0, 4);  s1 += __shfl_xor(s1, 4);
            s0 += __shfl_xor(s0, 8);  s1 += __shfl_xor(s1, 8);
            if (m == 0) {
                const int b = wv * 32 + bt * 16 + quad * 4 + r;
                float x0 = s0 + bb0;
                float x1 = s1 + bb1;
                ldsO[b] = x0 * sigmoidf(x1) * invT;
            }
        }
    }

    __syncthreads();

    // One coalesced 512B row per block into out_t (2048,128).
    if (t < 128)
        out_t[(size_t)n * 128 + t] = ldsO[t];
}

// Transpose out_t (2048,128) -> out (128,2048). 32x32 tiles, 256 blocks.
__global__ __launch_bounds__(256)
void transpose_kernel(const float* __restrict__ out_t, float* __restrict__ out)
{
    __shared__ float tile[32][33];
    const int t    = threadIdx.x;
    const int bidx = blockIdx.x;           // 0..255
    const int n0   = (bidx & 63) * 32;     // 64 n-tiles
    const int b0   = (bidx >> 6) * 32;     // 4 b-tiles

    const int tx = t & 31;
    const int ty = t >> 5;                 // 0..7

    #pragma unroll
    for (int i = 0; i < 4; ++i) {
        const int nl = ty + i * 8;
        tile[nl][tx] = out_t[(size_t)(n0 + nl) * 128 + b0 + tx];
    }

    __syncthreads();

    #pragma unroll
    for (int i = 0; i < 4; ++i) {
        const int bl = ty + i * 8;
        out[(size_t)(b0 + bl) * NN + n0 + tx] = tile[tx][bl];
    }
}

extern "C" void kernel_launch(void* const* d_in, const int* in_sizes, int n_in,
                              void* d_out, int out_size, void* d_ws, size_t ws_size,
                              hipStream_t stream) {
    const float* st = (const float*)d_in[0];
    const float* w1 = (const float*)d_in[1];
    const float* b1 = (const float*)d_in[2];
    const float* w2 = (const float*)d_in[3];
    const float* b2 = (const float*)d_in[4];
    const float* T  = (const float*)d_in[5];
    float* out   = (float*)d_out;
    float* out_t = (float*)d_ws;    // 2048*128*4 = 1 MB scratch

    nlm_kernel<<<dim3(NN), dim3(256), 0, stream>>>(st, w1, b1, w2, b2, T, out_t);
    transpose_kernel<<<dim3(256), dim3(256), 0, stream>>>(out_t, out);
}